// Round 6
// baseline (69.632 us; speedup 1.0000x reference)
//
#include <hip/hip_runtime.h>
#include <math.h>

#define NW 8

typedef float v2f __attribute__((ext_vector_type(2)));
__device__ __forceinline__ v2f mk2(float a, float b) { v2f r; r.x = a; r.y = b; return r; }

// ---- cross-lane exchanges: all DPP (VALU pipe, no DS) ----------------------
template<int CTRL>
__device__ __forceinline__ float dpp_x(float v) {
    return __int_as_float(
        __builtin_amdgcn_update_dpp(0, __float_as_int(v), CTRL, 0xF, 0xF, true));
}
template<int CTRL>
__device__ __forceinline__ v2f dpp2(v2f v) {
    v2f r; r.x = dpp_x<CTRL>(v.x); r.y = dpp_x<CTRL>(v.y); return r;
}
#define XCH1(v) dpp2<0xB1>(v)                 /* quad_perm [1,0,3,2] == XOR1 */
#define XCH2(v) dpp2<0x4E>(v)                 /* quad_perm [2,3,0,1] == XOR2 */
#define XCH8(v) dpp2<0x128>(v)                /* row_ror:8           == XOR8 */
#define XCH4(v) dpp2<0x1B>(dpp2<0x141>(v))    /* XOR3 o XOR7         == XOR4 */

// Layout: wave = 4 items (g = lane>>4). Sublane sl = lane&15 carries the
// amplitude high nibble; each lane holds 16 amplitudes packed as 8 float2.
//   n7<->sl bit0 (XOR1), n6<->sl bit1 (XOR2), n5<->sl bit3 (XOR8),
//   n4<->sl bit2 (XOR4 composite); n3..n1 = k bits 2..0 (in-lane),
//   n0 = within-vector axis (wire7). Wire i acts on n bit (7-i).
__global__ __launch_bounds__(256, 4) void vqc_kernel(
    const float* __restrict__ x,     // [B,8]
    const float* __restrict__ ry1,   // [8]
    const float* __restrict__ crz1,  // [8]
    const float* __restrict__ ry2,   // [8]
    const float* __restrict__ crz2,  // [8]
    float* __restrict__ out,         // [B,8]
    int B)
{
    // CRZ tables: 16 rows (per sl) x 16 floats padded to 20 (80B rows stay
    // 16B-aligned; 20*sl mod 32 -> 2-way bank aliasing = free).
    __shared__ __align__(16) float Tc1[320], Ts1[320], Tc2[320], Ts2[320];
    // RY param cos/sin: [0..7]=c1 [8..15]=s1 [16..23]=c2 [24..31]=s2
    __shared__ __align__(16) float Rp[32];

    const int t = threadIdx.x;
    {
        const int n = t;  // basis index 0..255
        float e1 = 0.f, e2 = 0.f;
#pragma unroll
        for (int i = 0; i < NW; ++i) {
            float bc  = (float)((n >> (7 - i)) & 1);
            float bt1 = (float)((n >> (7 - ((i + 1) & 7))) & 1);
            float bt2 = (float)((n >> (7 - ((i + 7) & 7))) & 1);
            e1 += bc * crz1[i] * (bt1 - 0.5f);
            e2 += bc * crz2[i] * (bt2 - 0.5f);
        }
        const int j  = n & 15;
        const int sl = ((n >> 7) & 1) | (((n >> 6) & 1) << 1)
                     | (((n >> 4) & 1) << 2) | (((n >> 5) & 1) << 3);
        const int idx = sl * 20 + j;
        float s, c;
        __sincosf(e1, &s, &c);  Tc1[idx] = c;  Ts1[idx] = s;
        __sincosf(e2, &s, &c);  Tc2[idx] = c;  Ts2[idx] = s;
        if (t < 8)       { __sincosf(0.5f * ry1[t], &s, &c);     Rp[t] = c;      Rp[8 + t] = s; }
        else if (t < 16) { __sincosf(0.5f * ry2[t - 8], &s, &c); Rp[8 + t] = c;  Rp[16 + t] = s; }
    }
    __syncthreads();

    const int lane = t & 63;
    const int sl   = lane & 15;
    const int g    = lane >> 4;

    // RY params from LDS (broadcast reads; saves 64 transcendentals/lane)
    float rc1[8], rs1[8], rc2[8], rs2[8];
    *(float4*)&rc1[0] = *(const float4*)&Rp[0];  *(float4*)&rc1[4] = *(const float4*)&Rp[4];
    *(float4*)&rs1[0] = *(const float4*)&Rp[8];  *(float4*)&rs1[4] = *(const float4*)&Rp[12];
    *(float4*)&rc2[0] = *(const float4*)&Rp[16]; *(float4*)&rc2[4] = *(const float4*)&Rp[20];
    *(float4*)&rs2[0] = *(const float4*)&Rp[24]; *(float4*)&rs2[4] = *(const float4*)&Rp[28];

    const float* pc1 = &Tc1[sl * 20];
    const float* ps1 = &Ts1[sl * 20];
    const float* pc2 = &Tc2[sl * 20];
    const float* ps2 = &Ts2[sl * 20];

    const int wavesPerBlock = blockDim.x >> 6;
    const int gwave = blockIdx.x * wavesPerBlock + (t >> 6);
    const int b  = gwave * 4 + g;
    const int bl = (b < B) ? b : (B - 1);

    // ---- encoding
    const float4* xp = (const float4*)(x + (size_t)bl * NW);
    float4 xa = xp[0], xb = xp[1];
    float cs[8], sn[8];
    __sincosf(0.5f * xa.x, &sn[0], &cs[0]);
    __sincosf(0.5f * xa.y, &sn[1], &cs[1]);
    __sincosf(0.5f * xa.z, &sn[2], &cs[2]);
    __sincosf(0.5f * xa.w, &sn[3], &cs[3]);
    __sincosf(0.5f * xb.x, &sn[4], &cs[4]);
    __sincosf(0.5f * xb.y, &sn[5], &cs[5]);
    __sincosf(0.5f * xb.z, &sn[6], &cs[6]);
    __sincosf(0.5f * xb.w, &sn[7], &cs[7]);

    // cross-lane factor: wire0<->sl bit0, wire1<->bit1, wire2<->bit3, wire3<->bit2
    float pcf = ((sl & 1) ? sn[0] : cs[0])
              * ((sl & 2) ? sn[1] : cs[1])
              * ((sl & 8) ? sn[2] : cs[2])
              * ((sl & 4) ? sn[3] : cs[3]);

    // in-lane outer product: k bit2->wire4, bit1->wire5, bit0->wire6; vec axis->wire7
    float t2[2], t4[4], t8[8];
    t2[0] = pcf * cs[4];  t2[1] = pcf * sn[4];
#pragma unroll
    for (int k = 0; k < 2; ++k) { t4[2*k] = t2[k] * cs[5];  t4[2*k+1] = t2[k] * sn[5]; }
#pragma unroll
    for (int k = 0; k < 4; ++k) { t8[2*k] = t4[k] * cs[6];  t8[2*k+1] = t4[k] * sn[6]; }

    const v2f cw7 = mk2(cs[7], sn[7]);
    v2f aP[8];
#pragma unroll
    for (int k = 0; k < 8; ++k) aP[k] = mk2(t8[k], t8[k]) * cw7;

    // ---- CRZ block 1 on real state: re = a*cos, im = a*sin
    v2f reP[8], imP[8];
#pragma unroll
    for (int q = 0; q < 4; ++q) {
        float4 cq = *(const float4*)&pc1[4 * q];
        float4 sq = *(const float4*)&ps1[4 * q];
        v2f cl = mk2(cq.x, cq.y), ch = mk2(cq.z, cq.w);
        v2f sl_ = mk2(sq.x, sq.y), sh = mk2(sq.z, sq.w);
        reP[2*q]   = aP[2*q]   * cl;  imP[2*q]   = aP[2*q]   * sl_;
        reP[2*q+1] = aP[2*q+1] * ch;  imP[2*q+1] = aP[2*q+1] * sh;
    }

#define CROSS_WIRE(RC, RS, WI, LBIT, EXCH)                                  \
    { float c_ = RC[WI], s_ = RS[WI];                                       \
      float se_ = (sl & LBIT) ? s_ : -s_;                                   \
      v2f cv = mk2(c_, c_), sev = mk2(se_, se_);                            \
      _Pragma("unroll")                                                     \
      for (int k = 0; k < 8; ++k) {                                         \
          v2f pre = EXCH(reP[k]);                                           \
          v2f pim = EXCH(imP[k]);                                           \
          reP[k] = reP[k] * cv + pre * sev;                                 \
          imP[k] = imP[k] * cv + pim * sev;                                 \
      } }

#define INLANE_WIRE(RC, RS, WI, M)                                          \
    { float c_ = RC[WI], s_ = RS[WI];                                       \
      v2f cv = mk2(c_, c_), sv = mk2(s_, s_);                               \
      _Pragma("unroll")                                                     \
      for (int k = 0; k < 8; ++k) if (!(k & M)) {                           \
          int h = k | M;                                                    \
          v2f rl = reP[k], rh = reP[h], il = imP[k], ih = imP[h];           \
          reP[k] = rl * cv - rh * sv;  reP[h] = rl * sv + rh * cv;          \
          imP[k] = il * cv - ih * sv;  imP[h] = il * sv + ih * cv;          \
      } }

#define WIRE7(RC, RS)                                                       \
    { float c_ = RC[7], s_ = RS[7];                                         \
      v2f cv = mk2(c_, c_), sev = mk2(-s_, s_);                             \
      _Pragma("unroll")                                                     \
      for (int k = 0; k < 8; ++k) {                                         \
          v2f r = reP[k], i = imP[k];                                       \
          v2f rsw = mk2(r.y, r.x), isw = mk2(i.y, i.x);                     \
          reP[k] = r * cv + rsw * sev;                                      \
          imP[k] = i * cv + isw * sev;                                      \
      } }

#define RY_LAYER(RC, RS)                                                    \
    do {                                                                    \
        CROSS_WIRE(RC, RS, 0, 1, XCH1);                                     \
        CROSS_WIRE(RC, RS, 1, 2, XCH2);                                     \
        CROSS_WIRE(RC, RS, 2, 8, XCH8);                                     \
        CROSS_WIRE(RC, RS, 3, 4, XCH4);                                     \
        INLANE_WIRE(RC, RS, 4, 4);                                          \
        INLANE_WIRE(RC, RS, 5, 2);                                          \
        INLANE_WIRE(RC, RS, 6, 1);                                          \
        WIRE7(RC, RS);                                                      \
    } while (0)

    // ---- RY layer 1
    RY_LAYER(rc1, rs1);

    // ---- CRZ block 2: complex multiply
#pragma unroll
    for (int q = 0; q < 4; ++q) {
        float4 cq = *(const float4*)&pc2[4 * q];
        float4 sq = *(const float4*)&ps2[4 * q];
        v2f cl = mk2(cq.x, cq.y), ch = mk2(cq.z, cq.w);
        v2f sl_ = mk2(sq.x, sq.y), sh = mk2(sq.z, sq.w);
        v2f r, i;
        r = reP[2*q];   i = imP[2*q];
        reP[2*q]   = r * cl - i * sl_;  imP[2*q]   = r * sl_ + i * cl;
        r = reP[2*q+1]; i = imP[2*q+1];
        reP[2*q+1] = r * ch - i * sh;   imP[2*q+1] = r * sh + i * ch;
    }

    // ---- RY layer 2
    RY_LAYER(rc2, rs2);

    // ---- probabilities + in-lane Walsh partials
    v2f pP[8];
#pragma unroll
    for (int k = 0; k < 8; ++k) pP[k] = reP[k] * reP[k] + imP[k] * imP[k];

    v2f s1v[4], dv6 = mk2(0.f, 0.f);
#pragma unroll
    for (int m = 0; m < 4; ++m) { s1v[m] = pP[2*m] + pP[2*m+1]; dv6 += pP[2*m] - pP[2*m+1]; }
    v2f s2v[2], dv5 = mk2(0.f, 0.f);
#pragma unroll
    for (int m = 0; m < 2; ++m) { s2v[m] = s1v[2*m] + s1v[2*m+1]; dv5 += s1v[2*m] - s1v[2*m+1]; }
    v2f sv0 = s2v[0] + s2v[1];
    v2f dv4 = s2v[0] - s2v[1];

    float v0 = sv0.x + sv0.y, d7 = sv0.x - sv0.y;
    float d4 = dv4.x + dv4.y, d5 = dv5.x + dv5.y, d6 = dv6.x + dv6.y;

    // ---- cross-lane Walsh butterfly over sl bits {0,1,2,3}
    v2f w1 = mk2(v0, d4), w2 = mk2(d5, d6);
    float w3 = d7;
#define BFLY_R(EXCH, EXCHS, M)                                              \
    { v2f o1 = EXCH(w1), o2 = EXCH(w2); float o3 = EXCHS(w3);               \
      if (sl & M) { w1 = o1 - w1; w2 = o2 - w2; w3 = o3 - w3; }             \
      else        { w1 = o1 + w1; w2 = o2 + w2; w3 = o3 + w3; } }
#define XS1(v) dpp_x<0xB1>(v)
#define XS2(v) dpp_x<0x4E>(v)
#define XS8(v) dpp_x<0x128>(v)
#define XS4(v) dpp_x<0x1B>(dpp_x<0x141>(v))
    BFLY_R(XCH1, XS1, 1);
    BFLY_R(XCH2, XS2, 2);
    BFLY_R(XCH4, XS4, 4);
    BFLY_R(XCH8, XS8, 8);
#undef BFLY_R

    // wire0 coeff at sl==1, wire1 at sl==2, wire2 at sl==8, wire3 at sl==4;
    // plain sums (wires 4..7) at sl==0.
    if (b < B) {
        float* ob = out + (size_t)b * NW;
        if      (sl == 0) *(float4*)(ob + 4) = make_float4(w1.y, w2.x, w2.y, w3);
        else if (sl == 1) ob[0] = w1.x;
        else if (sl == 2) ob[1] = w1.x;
        else if (sl == 8) ob[2] = w1.x;
        else if (sl == 4) ob[3] = w1.x;
    }
#undef RY_LAYER
#undef CROSS_WIRE
#undef INLANE_WIRE
#undef WIRE7
}

extern "C" void kernel_launch(void* const* d_in, const int* in_sizes, int n_in,
                              void* d_out, int out_size, void* d_ws, size_t ws_size,
                              hipStream_t stream) {
    const float* x    = (const float*)d_in[0];
    const float* ry1  = (const float*)d_in[1];
    const float* crz1 = (const float*)d_in[2];
    const float* ry2  = (const float*)d_in[3];
    const float* crz2 = (const float*)d_in[4];
    float* out = (float*)d_out;

    int B = in_sizes[0] / NW;                  // 16384
    // 4 items/wave, 4 waves/block -> 16 items/block -> 1024 blocks
    int blocks = (B + 15) / 16;
    if (blocks < 1) blocks = 1;
    vqc_kernel<<<blocks, 256, 0, stream>>>(x, ry1, crz1, ry2, crz2, out, B);
}